// Round 7
// baseline (410.031 us; speedup 1.0000x reference)
//
#include <hip/hip_runtime.h>
#include <hip/hip_bf16.h>
#include <hip/hip_fp16.h>

// 2-layer GCN, N=100000 nodes, E=3.2M edges, dims 128 -> 64 -> 2, fp32.
// R20: src-windowed layer-1 aggregation with R13's proven consumer shape.
// k_build sub-bins each node's edge segment by src>>15 (4 src ranges, each
// h1 slice = 4MiB = per-XCD L2). k_aggW: 1924 co-resident blocks (8/CU,
// launch_bounds(256,8)), 13 nodes/wave, acc in LDS; pass k walks only the
// k-th sub-segments -> chip-wide gathers confined to one L2-resident slice
// (R15 proved windowing drops FETCH 333->45MB/pass; R13's 8-broadcast +
// coalesced-128B-gather body is the proven-fast consumer). No grid barrier:
// co-resident start + +-10% per-pass work keeps phases naturally aligned.
// R19 wn-foldback dropped (A/B: net zero). prop2 reads rpx stride-4.

#define DIN  128
#define DHID 64
#define BSH  7                    // bucket shift: 128 nodes/bucket
#define BCAP 5000                 // k_build LDS staging capacity (edges)
#define SCHUNK 12544              // k_scatter LDS slot capacity (>= E/C)
#define BMAX 800                  // >= B = ceil(N/128) = 782
#define NPW  13                   // nodes per wave in k_aggW

typedef _Float16 half8 __attribute__((ext_vector_type(8)));
typedef float    f32x4 __attribute__((ext_vector_type(4)));

// ---------------- K1: per-chunk coarse histogram (4 LDS replicas) --
__global__ __launch_bounds__(1024) void k_hist(const int* __restrict__ ei,
                                               int* __restrict__ histT,
                                               int E, int chunk, int B, int C) {
    __shared__ int h[4][BMAX + 1];        // replicas bank-shifted (801 ints)
    for (int t = threadIdx.x; t < 4 * (BMAX + 1); t += 1024)
        ((int*)h)[t] = 0;
    __syncthreads();
    int c = blockIdx.x;
    int rep = (threadIdx.x >> 6) & 3;     // wave-group -> replica
    int e0 = c * chunk, e1 = min(E, e0 + chunk);
    for (int e = e0 + threadIdx.x; e < e1; e += 1024)
        atomicAdd(&h[rep][ei[E + e] >> BSH], 1);
    __syncthreads();
    for (int t = threadIdx.x; t < B; t += 1024)
        histT[(size_t)t * C + c] = h[0][t] + h[1][t] + h[2][t] + h[3][t];
}

// ------- K2: per-bucket exclusive scan over its C chunk-cells ------
__global__ __launch_bounds__(256) void k_scan1(int* __restrict__ histT,
                                               int* __restrict__ tot, int C) {
    __shared__ int sm[256];
    int b = blockIdx.x, t = threadIdx.x;
    size_t base = (size_t)b * C;
    int v = histT[base + t];
    sm[t] = v;
    __syncthreads();
    for (int off = 1; off < 256; off <<= 1) {
        int add = (t >= off) ? sm[t - off] : 0;
        __syncthreads();
        sm[t] += add;
        __syncthreads();
    }
    histT[base + t] = sm[t] - v;          // exclusive within bucket
    if (t == 255) tot[b] = sm[t];
}

// ------- K3: exclusive scan of bucket totals -> bucket bases -------
__global__ __launch_bounds__(1024) void k_scan2(const int* __restrict__ tot,
                                                int* __restrict__ bb, int B) {
    __shared__ int sm[1024];
    int t = threadIdx.x;
    int v = (t < B) ? tot[t] : 0;
    sm[t] = v;
    __syncthreads();
    for (int off = 1; off < 1024; off <<= 1) {
        int add = (t >= off) ? sm[t - off] : 0;
        __syncthreads();
        sm[t] += add;
        __syncthreads();
    }
    if (t < B) {
        bb[t] = sm[t] - v;
        if (t == B - 1) bb[B] = sm[t];
    }
}

// ---------------- K4: LDS slot-reordered scatter -------------------
__global__ __launch_bounds__(1024) void k_scatter(const int* __restrict__ ei,
                                                  const float* __restrict__ ew,
                                                  const int* __restrict__ histT,
                                                  const int* __restrict__ bb,
                                                  int2* __restrict__ ebuf,
                                                  int E, int chunk, int B, int C) {
    __shared__ int eidx[SCHUNK];          // 50 KB (also scan temp)
    __shared__ int lbase[BMAX];
    __shared__ int lcur[BMAX];
    __shared__ int gbase[BMAX];
    int c = blockIdx.x, t = threadIdx.x;
    int e0 = c * chunk, e1 = min(E, e0 + chunk), m = e1 - e0;

    for (int b = t; b < B; b += 1024) lcur[b] = 0;
    __syncthreads();
    // pass 1: per-bucket counts
    for (int q = t; q < m; q += 1024)
        atomicAdd(&lcur[ei[E + e0 + q] >> BSH], 1);
    __syncthreads();
    // scan counts (1024-wide Hillis-Steele in eidx[0..1023])
    int v = (t < B) ? lcur[t] : 0;
    eidx[t] = v;
    __syncthreads();
    for (int off = 1; off < 1024; off <<= 1) {
        int add = (t >= off) ? eidx[t - off] : 0;
        __syncthreads();
        eidx[t] += add;
        __syncthreads();
    }
    if (t < B) {
        lbase[t] = eidx[t] - v;
        gbase[t] = histT[(size_t)t * C + c] + bb[t];
        lcur[t] = 0;
    }
    __syncthreads();
    // pass 2: place edge indices into bucket-ordered slots (dst re-read L2-hot)
    for (int q = t; q < m; q += 1024) {
        int b = ei[E + e0 + q] >> BSH;
        int pos = lbase[b] + atomicAdd(&lcur[b], 1);
        eidx[pos] = q;
    }
    __syncthreads();
    // pass 3: slot-ordered writeout (consecutive slots -> consecutive ebuf)
    for (int q = t; q < m; q += 1024) {
        int e = e0 + eidx[q];
        int s = ei[e];
        int d = ei[E + e];
        float w = ew[e];
        int b = d >> BSH;
        int gpos = gbase[b] + (q - lbase[b]);
        ebuf[gpos] = make_int2(s | ((d & 127) << 24), __float_as_int(w));
    }
}

// ------- K5: per-bucket CSR build with src-range sub-binning -------
// Counts per (local node, src range k = src>>15), scans to absolute csw
// bases, writes rpx[node*4+k] boundaries, places edges node+range-grouped.
__global__ __launch_bounds__(512) void k_build(const int2* __restrict__ ebuf,
                                               const int* __restrict__ bb,
                                               int* __restrict__ rpx,
                                               float* __restrict__ dinv,
                                               int2* __restrict__ csw,
                                               int N, int E) {
    __shared__ int2  stage[BCAP];   // 40 KB
    __shared__ int   cnt[128][4];
    __shared__ float dsum4[4][132];
    __shared__ int   base2[128][4];
    __shared__ int   cur2[128][4];
    __shared__ int   sm[512];
    int b = blockIdx.x, t = threadIdx.x;
    if (t < 128) {
#pragma unroll
        for (int k = 0; k < 4; ++k) { cnt[t][k] = 0; cur2[t][k] = 0; }
    }
    dsum4[t >> 7][t & 127] = 0.0f;        // 512 threads cover 4x128
    __syncthreads();
    int p0 = bb[b], p1 = bb[b + 1];
    int m = p1 - p0;
    bool fits = (m <= BCAP);
    int rep = (t >> 6) & 3;               // wave-pair -> dsum replica
    for (int p = p0 + t; p < p1; p += 512) {
        int2 v = ebuf[p];
        if (fits) stage[p - p0] = v;
        int ln = (((unsigned)v.x) >> 24) & 127;
        int k  = (v.x & 0xFFFFFF) >> 15;
        atomicAdd(&cnt[ln][k], 1);
        atomicAdd(&dsum4[rep][ln], __int_as_float(v.y));
    }
    __syncthreads();
    // branch-free scan of 128 per-node totals (threads >=128 carry zeros)
    int cv = 0;
    if (t < 128) cv = cnt[t][0] + cnt[t][1] + cnt[t][2] + cnt[t][3];
    sm[t] = cv;
    __syncthreads();
    for (int off = 1; off < 128; off <<= 1) {
        int add = (t >= off) ? sm[t - off] : 0;
        __syncthreads();
        sm[t] += add;
        __syncthreads();
    }
    if (t < 128) {
        int lrp = sm[t] - cv + p0;        // absolute csw base for node t
        int d = (b << BSH) + t;
        int acc2 = lrp;
#pragma unroll
        for (int k = 0; k < 4; ++k) {
            base2[t][k] = acc2;
            if (d < N) rpx[d * 4 + k] = acc2;
            acc2 += cnt[t][k];
        }
        if (d < N) {
            float ds = dsum4[0][t] + dsum4[1][t] + dsum4[2][t] + dsum4[3][t];
            dinv[d] = rsqrtf(1.0f + ds);
        }
    }
    if (b == 0 && t == 0) rpx[4 * N] = E;
    __syncthreads();
    for (int q = t; q < m; q += 512) {
        int2 v = fits ? stage[q] : ebuf[p0 + q];
        int ln = (((unsigned)v.x) >> 24) & 127;
        int s  = v.x & 0xFFFFFF;
        int k  = s >> 15;
        int r = atomicAdd(&cur2[ln][k], 1);   // LDS atomic
        csw[base2[ln][k] + r] = make_int2(s, v.y);  // (src, raw w)
    }
}

// ---------------- K6: h1 = fp16(x @ W1) via MFMA (W1 conv inline) --
__global__ __launch_bounds__(256) void k_gemm1(const float* __restrict__ x,
                                               const float* __restrict__ W1,
                                               __half* __restrict__ h1, int N) {
    __shared__ _Float16 As[64][136];
    __shared__ _Float16 Bs[64][136];   // Bs[col][k]
    int t = threadIdx.x;
    int wave = t >> 6, lane = t & 63;
    int r0 = blockIdx.x * 64;

    for (int idx = t; idx < DIN * DHID; idx += 256) {
        int k = idx >> 6, c = idx & 63;
        Bs[c][k] = (_Float16)W1[idx];          // W1 32KB -> L2-resident
    }
    const float4* xv = (const float4*)x;
    for (int idx = t; idx < 64 * 32; idx += 256) {
        int r = idx >> 5, c4 = idx & 31;
        int rr = r0 + r;
        float4 v = (rr < N) ? xv[(size_t)rr * 32 + c4]
                            : make_float4(0.f, 0.f, 0.f, 0.f);
        As[r][c4 * 4 + 0] = (_Float16)v.x;
        As[r][c4 * 4 + 1] = (_Float16)v.y;
        As[r][c4 * 4 + 2] = (_Float16)v.z;
        As[r][c4 * 4 + 3] = (_Float16)v.w;
    }
    __syncthreads();

    int row = lane & 15;
    int kg  = lane >> 4;
    f32x4 acc0 = {0.f,0.f,0.f,0.f}, acc1 = {0.f,0.f,0.f,0.f};
    f32x4 acc2 = {0.f,0.f,0.f,0.f}, acc3 = {0.f,0.f,0.f,0.f};
#pragma unroll
    for (int kc = 0; kc < 4; ++kc) {
        half8 a = *(const half8*)&As[wave * 16 + row][kc * 32 + kg * 8];
        half8 b0 = *(const half8*)&Bs[ 0 + row][kc * 32 + kg * 8];
        half8 b1 = *(const half8*)&Bs[16 + row][kc * 32 + kg * 8];
        half8 b2 = *(const half8*)&Bs[32 + row][kc * 32 + kg * 8];
        half8 b3 = *(const half8*)&Bs[48 + row][kc * 32 + kg * 8];
        acc0 = __builtin_amdgcn_mfma_f32_16x16x32_f16(a, b0, acc0, 0, 0, 0);
        acc1 = __builtin_amdgcn_mfma_f32_16x16x32_f16(a, b1, acc1, 0, 0, 0);
        acc2 = __builtin_amdgcn_mfma_f32_16x16x32_f16(a, b2, acc2, 0, 0, 0);
        acc3 = __builtin_amdgcn_mfma_f32_16x16x32_f16(a, b3, acc3, 0, 0, 0);
    }
#pragma unroll
    for (int reg = 0; reg < 4; ++reg) {
        int rr = r0 + wave * 16 + kg * 4 + reg;
        if (rr < N) {
            int col = lane & 15;
            size_t base = (size_t)rr * DHID;
            h1[base + col +  0] = __float2half(acc0[reg]);
            h1[base + col + 16] = __float2half(acc1[reg]);
            h1[base + col + 32] = __float2half(acc2[reg]);
            h1[base + col + 48] = __float2half(acc3[reg]);
        }
    }
}

// ------- K7: src-windowed layer-1 aggregate + bias + ReLU + @W2 ----
// Co-resident grid (8 blocks/CU); 13 nodes/wave, acc in LDS. Pass k
// walks only src-range-k sub-segments -> gathers hit the 4MiB h1 slice
// resident in each XCD's L2. Inner body = R13's proven 8-broadcast +
// coalesced-128B-gather shape.
__global__ __launch_bounds__(256, 8) void k_aggW(const __half* __restrict__ h1h,
                                                 const int* __restrict__ rpx,
                                                 const int2* __restrict__ csw,
                                                 const float* __restrict__ dinv,
                                                 const float* __restrict__ b1,
                                                 const float* __restrict__ W2,
                                                 float* __restrict__ h2, int N) {
    __shared__ float accs[4][NPW][64];    // 13.3 KB
    int t = threadIdx.x, lane = t & 63, wl = t >> 6;
    int i0 = (blockIdx.x * 4 + wl) * NPW;
    for (int j = 0; j < NPW; ++j) accs[wl][j][lane] = 0.0f;
    for (int k = 0; k < 4; ++k) {
        for (int j = 0; j < NPW; ++j) {
            int i = i0 + j;
            if (i >= N) break;
            int p  = __builtin_amdgcn_readfirstlane(rpx[i * 4 + k]);
            int pe = __builtin_amdgcn_readfirstlane(rpx[i * 4 + k + 1]);
            float acc = 0.0f;
            for (; p + 8 <= pe; p += 8) {
                int2 eA = csw[p],     eB = csw[p + 1], eC = csw[p + 2], eD = csw[p + 3];
                int2 eE = csw[p + 4], eF = csw[p + 5], eG = csw[p + 6], eH = csw[p + 7];
                int sA = __builtin_amdgcn_readfirstlane(eA.x);
                int sB = __builtin_amdgcn_readfirstlane(eB.x);
                int sC = __builtin_amdgcn_readfirstlane(eC.x);
                int sD = __builtin_amdgcn_readfirstlane(eD.x);
                int sE = __builtin_amdgcn_readfirstlane(eE.x);
                int sF = __builtin_amdgcn_readfirstlane(eF.x);
                int sG = __builtin_amdgcn_readfirstlane(eG.x);
                int sH = __builtin_amdgcn_readfirstlane(eH.x);
                float wA = __uint_as_float(__builtin_amdgcn_readfirstlane(eA.y)) * dinv[sA];
                float wB = __uint_as_float(__builtin_amdgcn_readfirstlane(eB.y)) * dinv[sB];
                float wC = __uint_as_float(__builtin_amdgcn_readfirstlane(eC.y)) * dinv[sC];
                float wD = __uint_as_float(__builtin_amdgcn_readfirstlane(eD.y)) * dinv[sD];
                float wE = __uint_as_float(__builtin_amdgcn_readfirstlane(eE.y)) * dinv[sE];
                float wF = __uint_as_float(__builtin_amdgcn_readfirstlane(eF.y)) * dinv[sF];
                float wG = __uint_as_float(__builtin_amdgcn_readfirstlane(eG.y)) * dinv[sG];
                float wH = __uint_as_float(__builtin_amdgcn_readfirstlane(eH.y)) * dinv[sH];
                float hA = __half2float(h1h[(size_t)sA * DHID + lane]);
                float hB = __half2float(h1h[(size_t)sB * DHID + lane]);
                float hC = __half2float(h1h[(size_t)sC * DHID + lane]);
                float hD = __half2float(h1h[(size_t)sD * DHID + lane]);
                float hE = __half2float(h1h[(size_t)sE * DHID + lane]);
                float hF = __half2float(h1h[(size_t)sF * DHID + lane]);
                float hG = __half2float(h1h[(size_t)sG * DHID + lane]);
                float hH = __half2float(h1h[(size_t)sH * DHID + lane]);
                acc = fmaf(wA, hA, acc);
                acc = fmaf(wB, hB, acc);
                acc = fmaf(wC, hC, acc);
                acc = fmaf(wD, hD, acc);
                acc = fmaf(wE, hE, acc);
                acc = fmaf(wF, hF, acc);
                acc = fmaf(wG, hG, acc);
                acc = fmaf(wH, hH, acc);
            }
            for (; p + 4 <= pe; p += 4) {
                int2 eA = csw[p], eB = csw[p + 1], eC = csw[p + 2], eD = csw[p + 3];
                int sA = __builtin_amdgcn_readfirstlane(eA.x);
                int sB = __builtin_amdgcn_readfirstlane(eB.x);
                int sC = __builtin_amdgcn_readfirstlane(eC.x);
                int sD = __builtin_amdgcn_readfirstlane(eD.x);
                float wA = __uint_as_float(__builtin_amdgcn_readfirstlane(eA.y)) * dinv[sA];
                float wB = __uint_as_float(__builtin_amdgcn_readfirstlane(eB.y)) * dinv[sB];
                float wC = __uint_as_float(__builtin_amdgcn_readfirstlane(eC.y)) * dinv[sC];
                float wD = __uint_as_float(__builtin_amdgcn_readfirstlane(eD.y)) * dinv[sD];
                float hA = __half2float(h1h[(size_t)sA * DHID + lane]);
                float hB = __half2float(h1h[(size_t)sB * DHID + lane]);
                float hC = __half2float(h1h[(size_t)sC * DHID + lane]);
                float hD = __half2float(h1h[(size_t)sD * DHID + lane]);
                acc = fmaf(wA, hA, acc);
                acc = fmaf(wB, hB, acc);
                acc = fmaf(wC, hC, acc);
                acc = fmaf(wD, hD, acc);
            }
            for (; p < pe; ++p) {
                int2 eA = csw[p];
                int sA = __builtin_amdgcn_readfirstlane(eA.x);
                float wA = __uint_as_float(__builtin_amdgcn_readfirstlane(eA.y)) * dinv[sA];
                acc = fmaf(wA, __half2float(h1h[(size_t)sA * DHID + lane]), acc);
            }
            accs[wl][j][lane] += acc;
        }
        __syncthreads();                  // keep block's waves phase-aligned
    }
    // epilogue: a = relu(di*(acc + di*self) + b1); h2 = a @ W2
    float bias = b1[lane];
    float w2a = W2[lane * 2], w2b = W2[lane * 2 + 1];
    for (int j = 0; j < NPW; ++j) {
        int i = i0 + j;
        if (i >= N) break;
        float di = dinv[i];
        float self = __half2float(h1h[(size_t)i * DHID + lane]);
        float a = (accs[wl][j][lane] + di * self) * di;
        a = fmaxf(a + bias, 0.0f);
        float o0 = a * w2a, o1 = a * w2b;
        for (int off = 32; off > 0; off >>= 1) {
            o0 += __shfl_xor(o0, off);
            o1 += __shfl_xor(o1, off);
        }
        if (lane == 0) {
            h2[i * 2]     = o0;
            h2[i * 2 + 1] = o1;
        }
    }
}

// ------- K8: layer-2 propagate: out = di*(sum + di*self) + b2 ------
__global__ __launch_bounds__(256) void k_prop2(const float* __restrict__ h2,
                                               const int* __restrict__ rpx,
                                               const int2* __restrict__ csw,
                                               const float* __restrict__ dinv,
                                               const float* __restrict__ b2,
                                               float* __restrict__ out, int N) {
    const float2* h2v = (const float2*)h2;
    int lane = threadIdx.x & 63;
    int i = (blockIdx.x * 256 + threadIdx.x) >> 6;
    if (i >= N) return;
    int s0 = rpx[i * 4], e0 = rpx[i * 4 + 4];
    float a0 = 0.0f, a1 = 0.0f;
    for (int p = s0 + lane; p < e0; p += 64) {
        int2 ed = csw[p];
        float w = __int_as_float(ed.y) * dinv[ed.x];  // raw w * dinv[src]
        float2 hv = h2v[ed.x];
        a0 = fmaf(w, hv.x, a0);
        a1 = fmaf(w, hv.y, a1);
    }
    for (int off = 32; off > 0; off >>= 1) {
        a0 += __shfl_xor(a0, off);
        a1 += __shfl_xor(a1, off);
    }
    if (lane == 0) {
        float di = dinv[i];
        out[i * 2]     = di * (a0 + di * h2[i * 2])     + b2[0];
        out[i * 2 + 1] = di * (a1 + di * h2[i * 2 + 1]) + b2[1];
    }
}

extern "C" void kernel_launch(void* const* d_in, const int* in_sizes, int n_in,
                              void* d_out, int out_size, void* d_ws, size_t ws_size,
                              hipStream_t stream) {
    const float* x  = (const float*)d_in[0];
    const int*   ei = (const int*)d_in[1];     // int32 per harness contract
    const float* ew = (const float*)d_in[2];
    const float* W1 = (const float*)d_in[3];
    const float* b1 = (const float*)d_in[4];
    const float* W2 = (const float*)d_in[5];
    const float* b2 = (const float*)d_in[6];
    float* out = (float*)d_out;

    const int N = in_sizes[0] / DIN;   // 100000
    const int E = in_sizes[2];         // 3200000

    const int C = 256;                 // edge chunks (12.5K edges each)
    const int B = (N + 127) >> BSH;    // 782 buckets of 128 nodes
    const int chunk = (E + C - 1) / C;

    // workspace layout (~54 MB; ebuf aliased by h1/h2 after k_build)
    char* w0 = (char*)d_ws;
    float* dinv  = (float*)w0;                      // N floats
    int*   rpx   = (int*)(dinv + N);                // 4N+8 ints (1.6 MB)
    int*   histT = rpx + (4 * N + 8);               // B*C ints (800 KB)
    int*   tot   = histT + (size_t)B * C;           // B ints
    int*   bb    = tot + B;                         // B+1 ints
    size_t off_csw = ((size_t)((char*)(bb + B + 1) - w0) + 15) & ~(size_t)15;
    int2*  csw  = (int2*)(w0 + off_csw);            // E pairs (25.6 MB)
    int2*  ebuf = csw + E;                          // E pairs (25.6 MB)
    __half* h1  = (__half*)ebuf;                    // alias: N*64 fp16 (12.8 MB)
    float* h2   = (float*)(h1 + (size_t)N * DHID);  // alias: N*2 fp32

    k_hist<<<C, 1024, 0, stream>>>(ei, histT, E, chunk, B, C);
    k_scan1<<<B, 256, 0, stream>>>(histT, tot, C);
    k_scan2<<<1, 1024, 0, stream>>>(tot, bb, B);
    k_scatter<<<C, 1024, 0, stream>>>(ei, ew, histT, bb, ebuf, E, chunk, B, C);
    k_build<<<B, 512, 0, stream>>>(ebuf, bb, rpx, dinv, csw, N, E);

    const int GB = (N + 63) / 64;
    k_gemm1<<<GB, 256, 0, stream>>>(x, W1, h1, N);

    const int WAVES = (N + NPW - 1) / NPW;          // 7693 waves
    const int GAW = (WAVES + 3) / 4;                // 1924 blocks (<=8/CU)
    k_aggW<<<GAW, 256, 0, stream>>>(h1, rpx, csw, dinv, b1, W2, h2, N);

    const int GW = ((size_t)N * 64 + 255) / 256;    // one wave per node
    k_prop2<<<GW, 256, 0, stream>>>(h2, rpx, csw, dinv, b2, out, N);
}

// Round 8
// 357.087 us; speedup vs baseline: 1.1483x; 1.1483x over previous
//
#include <hip/hip_runtime.h>
#include <hip/hip_bf16.h>
#include <hip/hip_fp16.h>

// 2-layer GCN, N=100000 nodes, E=3.2M edges, dims 128 -> 64 -> 2, fp32.
// R21 = R18 (best, 380us) with preprocessing parallelism raised; agg1/prop2/
// gemm1 untouched (k_agg1 pinned at 107.5us random-line ceiling; windowing
// attempts R14/R15/R16/R20 all lost more issue-rate than they saved bytes).
// Rest-of-pipeline runs ~260us for ~230MB stream (~0.9TB/s) -> occupancy,
// not bytes, is the limiter there:
//  (1) C 256->512: k_hist/k_scatter grids = 512 = 2 blocks/CU (was exactly
//      1/CU for scatter -> every syncthreads stall idled the CU); scatter
//      LDS 60->35KB makes the 2nd block fit; per-block sync chain halves.
//  (2) k_build 512->1024 threads (4 edge-iters/pass, 2 blocks/CU, 32 waves).
//  (3) k_scan1 512 threads to match C=512.

#define DIN  128
#define DHID 64
#define BSH  7                    // bucket shift: 128 nodes/bucket
#define BCAP 5000                 // k_build LDS staging capacity (edges)
#define SCHUNK 6272               // k_scatter LDS slot capacity (>= E/C)
#define BMAX 800                  // >= B = ceil(N/128) = 782

typedef _Float16 half8 __attribute__((ext_vector_type(8)));
typedef float    f32x4 __attribute__((ext_vector_type(4)));

// ---------------- K1: per-chunk coarse histogram (4 LDS replicas) --
__global__ __launch_bounds__(1024) void k_hist(const int* __restrict__ ei,
                                               int* __restrict__ histT,
                                               int E, int chunk, int B, int C) {
    __shared__ int h[4][BMAX + 1];        // replicas bank-shifted (801 ints)
    for (int t = threadIdx.x; t < 4 * (BMAX + 1); t += 1024)
        ((int*)h)[t] = 0;
    __syncthreads();
    int c = blockIdx.x;
    int rep = (threadIdx.x >> 6) & 3;     // wave-group -> replica
    int e0 = c * chunk, e1 = min(E, e0 + chunk);
    for (int e = e0 + threadIdx.x; e < e1; e += 1024)
        atomicAdd(&h[rep][ei[E + e] >> BSH], 1);
    __syncthreads();
    for (int t = threadIdx.x; t < B; t += 1024)
        histT[(size_t)t * C + c] = h[0][t] + h[1][t] + h[2][t] + h[3][t];
}

// ------- K2: per-bucket exclusive scan over its C chunk-cells ------
__global__ __launch_bounds__(512) void k_scan1(int* __restrict__ histT,
                                               int* __restrict__ tot, int C) {
    __shared__ int sm[512];
    int b = blockIdx.x, t = threadIdx.x;
    size_t base = (size_t)b * C;
    int v = histT[base + t];
    sm[t] = v;
    __syncthreads();
    for (int off = 1; off < 512; off <<= 1) {
        int add = (t >= off) ? sm[t - off] : 0;
        __syncthreads();
        sm[t] += add;
        __syncthreads();
    }
    histT[base + t] = sm[t] - v;          // exclusive within bucket
    if (t == 511) tot[b] = sm[t];
}

// ------- K3: exclusive scan of bucket totals -> bucket bases -------
__global__ __launch_bounds__(1024) void k_scan2(const int* __restrict__ tot,
                                                int* __restrict__ bb, int B) {
    __shared__ int sm[1024];
    int t = threadIdx.x;
    int v = (t < B) ? tot[t] : 0;
    sm[t] = v;
    __syncthreads();
    for (int off = 1; off < 1024; off <<= 1) {
        int add = (t >= off) ? sm[t - off] : 0;
        __syncthreads();
        sm[t] += add;
        __syncthreads();
    }
    if (t < B) {
        bb[t] = sm[t] - v;
        if (t == B - 1) bb[B] = sm[t];
    }
}

// ---------------- K4: LDS slot-reordered scatter -------------------
// Per chunk: count -> scan -> place edge-INDICES into bucket-ordered
// LDS slots -> slot-ordered coalesced writeout to ebuf (full-line bursts).
__global__ __launch_bounds__(1024) void k_scatter(const int* __restrict__ ei,
                                                  const float* __restrict__ ew,
                                                  const int* __restrict__ histT,
                                                  const int* __restrict__ bb,
                                                  int2* __restrict__ ebuf,
                                                  int E, int chunk, int B, int C) {
    __shared__ int eidx[SCHUNK];          // 25 KB (also scan temp)
    __shared__ int lbase[BMAX];
    __shared__ int lcur[BMAX];
    __shared__ int gbase[BMAX];
    int c = blockIdx.x, t = threadIdx.x;
    int e0 = c * chunk, e1 = min(E, e0 + chunk), m = e1 - e0;

    for (int b = t; b < B; b += 1024) lcur[b] = 0;
    __syncthreads();
    // pass 1: per-bucket counts
    for (int q = t; q < m; q += 1024)
        atomicAdd(&lcur[ei[E + e0 + q] >> BSH], 1);
    __syncthreads();
    // scan counts (1024-wide Hillis-Steele in eidx[0..1023])
    int v = (t < B) ? lcur[t] : 0;
    eidx[t] = v;
    __syncthreads();
    for (int off = 1; off < 1024; off <<= 1) {
        int add = (t >= off) ? eidx[t - off] : 0;
        __syncthreads();
        eidx[t] += add;
        __syncthreads();
    }
    if (t < B) {
        lbase[t] = eidx[t] - v;
        gbase[t] = histT[(size_t)t * C + c] + bb[t];
        lcur[t] = 0;
    }
    __syncthreads();
    // pass 2: place edge indices into bucket-ordered slots (dst re-read L2-hot)
    for (int q = t; q < m; q += 1024) {
        int b = ei[E + e0 + q] >> BSH;
        int pos = lbase[b] + atomicAdd(&lcur[b], 1);
        eidx[pos] = q;
    }
    __syncthreads();
    // pass 3: slot-ordered writeout (consecutive slots -> consecutive ebuf)
    for (int q = t; q < m; q += 1024) {
        int e = e0 + eidx[q];
        int s = ei[e];
        int d = ei[E + e];
        float w = ew[e];
        int b = d >> BSH;
        int gpos = gbase[b] + (q - lbase[b]);
        ebuf[gpos] = make_int2(s | ((d & 127) << 24), __float_as_int(w));
    }
}

// ---------------- K5: per-bucket CSR build (rp, dinv, csw) ---------
// 1024 threads (4 edge-iters/pass, 2 blocks/CU); 4x replicated cnt/dsum
// to cut same-address LDS atomic serialization.
__global__ __launch_bounds__(1024) void k_build(const int2* __restrict__ ebuf,
                                                const int* __restrict__ bb,
                                                int* __restrict__ rp,
                                                float* __restrict__ dinv,
                                                int2* __restrict__ csw,
                                                int N, int E) {
    __shared__ int2  stage[BCAP];   // 40 KB
    __shared__ int   cnt4[4][132];
    __shared__ float dsum4[4][132];
    __shared__ int   lrp[128];
    __shared__ int   cur[128];
    __shared__ int   sm[1024];
    int b = blockIdx.x, t = threadIdx.x;
    if (t < 128) {
#pragma unroll
        for (int r = 0; r < 4; ++r) { cnt4[r][t] = 0; dsum4[r][t] = 0.0f; }
        cur[t] = 0;
    }
    __syncthreads();
    int p0 = bb[b], p1 = bb[b + 1];
    int m = p1 - p0;
    bool fits = (m <= BCAP);
    int rep = (t >> 6) & 3;               // wave -> replica (cyclic)
    for (int p = p0 + t; p < p1; p += 1024) {
        int2 v = ebuf[p];
        if (fits) stage[p - p0] = v;
        int ln = (((unsigned)v.x) >> 24) & 127;
        atomicAdd(&cnt4[rep][ln], 1);
        atomicAdd(&dsum4[rep][ln], __int_as_float(v.y));
    }
    __syncthreads();
    // branch-free scan of 128 reduced counts (threads >=128 carry zeros)
    int cv = 0;
    if (t < 128) cv = cnt4[0][t] + cnt4[1][t] + cnt4[2][t] + cnt4[3][t];
    sm[t] = cv;
    __syncthreads();
    for (int off = 1; off < 128; off <<= 1) {
        int add = (t >= off) ? sm[t - off] : 0;
        __syncthreads();
        sm[t] += add;
        __syncthreads();
    }
    if (t < 128) {
        lrp[t] = sm[t] - cv + p0;     // absolute csw base for local node t
        int d = (b << BSH) + t;
        if (d < N) {
            rp[d]   = lrp[t];
            float ds = dsum4[0][t] + dsum4[1][t] + dsum4[2][t] + dsum4[3][t];
            dinv[d] = rsqrtf(1.0f + ds);
        }
    }
    if (b == 0 && t == 0) rp[N] = E;
    __syncthreads();
    for (int q = t; q < m; q += 1024) {
        int2 v = fits ? stage[q] : ebuf[p0 + q];
        int ln = (((unsigned)v.x) >> 24) & 127;
        int r = atomicAdd(&cur[ln], 1);   // LDS atomic
        csw[lrp[ln] + r] = make_int2(v.x & 0xFFFFFF, v.y);  // raw w
    }
}

// ---------------- K6: h1 = fp16(x @ W1) via MFMA (W1 conv inline) --
__global__ __launch_bounds__(256) void k_gemm1(const float* __restrict__ x,
                                               const float* __restrict__ W1,
                                               __half* __restrict__ h1, int N) {
    __shared__ _Float16 As[64][136];
    __shared__ _Float16 Bs[64][136];   // Bs[col][k]
    int t = threadIdx.x;
    int wave = t >> 6, lane = t & 63;
    int r0 = blockIdx.x * 64;

    for (int idx = t; idx < DIN * DHID; idx += 256) {
        int k = idx >> 6, c = idx & 63;
        Bs[c][k] = (_Float16)W1[idx];          // W1 32KB -> L2-resident
    }
    const float4* xv = (const float4*)x;
    for (int idx = t; idx < 64 * 32; idx += 256) {
        int r = idx >> 5, c4 = idx & 31;
        int rr = r0 + r;
        float4 v = (rr < N) ? xv[(size_t)rr * 32 + c4]
                            : make_float4(0.f, 0.f, 0.f, 0.f);
        As[r][c4 * 4 + 0] = (_Float16)v.x;
        As[r][c4 * 4 + 1] = (_Float16)v.y;
        As[r][c4 * 4 + 2] = (_Float16)v.z;
        As[r][c4 * 4 + 3] = (_Float16)v.w;
    }
    __syncthreads();

    int row = lane & 15;
    int kg  = lane >> 4;
    f32x4 acc0 = {0.f,0.f,0.f,0.f}, acc1 = {0.f,0.f,0.f,0.f};
    f32x4 acc2 = {0.f,0.f,0.f,0.f}, acc3 = {0.f,0.f,0.f,0.f};
#pragma unroll
    for (int kc = 0; kc < 4; ++kc) {
        half8 a = *(const half8*)&As[wave * 16 + row][kc * 32 + kg * 8];
        half8 b0 = *(const half8*)&Bs[ 0 + row][kc * 32 + kg * 8];
        half8 b1 = *(const half8*)&Bs[16 + row][kc * 32 + kg * 8];
        half8 b2 = *(const half8*)&Bs[32 + row][kc * 32 + kg * 8];
        half8 b3 = *(const half8*)&Bs[48 + row][kc * 32 + kg * 8];
        acc0 = __builtin_amdgcn_mfma_f32_16x16x32_f16(a, b0, acc0, 0, 0, 0);
        acc1 = __builtin_amdgcn_mfma_f32_16x16x32_f16(a, b1, acc1, 0, 0, 0);
        acc2 = __builtin_amdgcn_mfma_f32_16x16x32_f16(a, b2, acc2, 0, 0, 0);
        acc3 = __builtin_amdgcn_mfma_f32_16x16x32_f16(a, b3, acc3, 0, 0, 0);
    }
#pragma unroll
    for (int reg = 0; reg < 4; ++reg) {
        int rr = r0 + wave * 16 + kg * 4 + reg;
        if (rr < N) {
            int col = lane & 15;
            size_t base = (size_t)rr * DHID;
            h1[base + col +  0] = __float2half(acc0[reg]);
            h1[base + col + 16] = __float2half(acc1[reg]);
            h1[base + col + 32] = __float2half(acc2[reg]);
            h1[base + col + 48] = __float2half(acc3[reg]);
        }
    }
}

// ------- K7: fused layer-1 aggregate + bias + ReLU + @W2 -----------
__global__ __launch_bounds__(256) void k_agg1(const __half* __restrict__ h1h,
                                              const int* __restrict__ rp,
                                              const int2* __restrict__ csw,
                                              const float* __restrict__ dinv,
                                              const float* __restrict__ b1,
                                              const float* __restrict__ W2,
                                              float* __restrict__ h2, int N) {
    int lane = threadIdx.x & 63;
    int i = (blockIdx.x * 256 + threadIdx.x) >> 6;
    if (i >= N) return;
    float bias = b1[lane];
    float w2a = W2[lane * 2];
    float w2b = W2[lane * 2 + 1];
    int s0 = __builtin_amdgcn_readfirstlane(rp[i]);
    int e0 = __builtin_amdgcn_readfirstlane(rp[i + 1]);
    float acc = 0.0f;
    int p = s0;
    for (; p + 8 <= e0; p += 8) {
        int2 eA = csw[p],     eB = csw[p + 1], eC = csw[p + 2], eD = csw[p + 3];
        int2 eE = csw[p + 4], eF = csw[p + 5], eG = csw[p + 6], eH = csw[p + 7];
        int sA = __builtin_amdgcn_readfirstlane(eA.x);
        int sB = __builtin_amdgcn_readfirstlane(eB.x);
        int sC = __builtin_amdgcn_readfirstlane(eC.x);
        int sD = __builtin_amdgcn_readfirstlane(eD.x);
        int sE = __builtin_amdgcn_readfirstlane(eE.x);
        int sF = __builtin_amdgcn_readfirstlane(eF.x);
        int sG = __builtin_amdgcn_readfirstlane(eG.x);
        int sH = __builtin_amdgcn_readfirstlane(eH.x);
        float wA = __uint_as_float(__builtin_amdgcn_readfirstlane(eA.y)) * dinv[sA];
        float wB = __uint_as_float(__builtin_amdgcn_readfirstlane(eB.y)) * dinv[sB];
        float wC = __uint_as_float(__builtin_amdgcn_readfirstlane(eC.y)) * dinv[sC];
        float wD = __uint_as_float(__builtin_amdgcn_readfirstlane(eD.y)) * dinv[sD];
        float wE = __uint_as_float(__builtin_amdgcn_readfirstlane(eE.y)) * dinv[sE];
        float wF = __uint_as_float(__builtin_amdgcn_readfirstlane(eF.y)) * dinv[sF];
        float wG = __uint_as_float(__builtin_amdgcn_readfirstlane(eG.y)) * dinv[sG];
        float wH = __uint_as_float(__builtin_amdgcn_readfirstlane(eH.y)) * dinv[sH];
        float hA = __half2float(h1h[(size_t)sA * DHID + lane]);
        float hB = __half2float(h1h[(size_t)sB * DHID + lane]);
        float hC = __half2float(h1h[(size_t)sC * DHID + lane]);
        float hD = __half2float(h1h[(size_t)sD * DHID + lane]);
        float hE = __half2float(h1h[(size_t)sE * DHID + lane]);
        float hF = __half2float(h1h[(size_t)sF * DHID + lane]);
        float hG = __half2float(h1h[(size_t)sG * DHID + lane]);
        float hH = __half2float(h1h[(size_t)sH * DHID + lane]);
        acc = fmaf(wA, hA, acc);
        acc = fmaf(wB, hB, acc);
        acc = fmaf(wC, hC, acc);
        acc = fmaf(wD, hD, acc);
        acc = fmaf(wE, hE, acc);
        acc = fmaf(wF, hF, acc);
        acc = fmaf(wG, hG, acc);
        acc = fmaf(wH, hH, acc);
    }
    for (; p + 4 <= e0; p += 4) {
        int2 eA = csw[p], eB = csw[p + 1], eC = csw[p + 2], eD = csw[p + 3];
        int sA = __builtin_amdgcn_readfirstlane(eA.x);
        int sB = __builtin_amdgcn_readfirstlane(eB.x);
        int sC = __builtin_amdgcn_readfirstlane(eC.x);
        int sD = __builtin_amdgcn_readfirstlane(eD.x);
        float wA = __uint_as_float(__builtin_amdgcn_readfirstlane(eA.y)) * dinv[sA];
        float wB = __uint_as_float(__builtin_amdgcn_readfirstlane(eB.y)) * dinv[sB];
        float wC = __uint_as_float(__builtin_amdgcn_readfirstlane(eC.y)) * dinv[sC];
        float wD = __uint_as_float(__builtin_amdgcn_readfirstlane(eD.y)) * dinv[sD];
        float hA = __half2float(h1h[(size_t)sA * DHID + lane]);
        float hB = __half2float(h1h[(size_t)sB * DHID + lane]);
        float hC = __half2float(h1h[(size_t)sC * DHID + lane]);
        float hD = __half2float(h1h[(size_t)sD * DHID + lane]);
        acc = fmaf(wA, hA, acc);
        acc = fmaf(wB, hB, acc);
        acc = fmaf(wC, hC, acc);
        acc = fmaf(wD, hD, acc);
    }
    for (; p < e0; ++p) {
        int2 eA = csw[p];
        int sA = __builtin_amdgcn_readfirstlane(eA.x);
        float wA = __uint_as_float(__builtin_amdgcn_readfirstlane(eA.y)) * dinv[sA];
        acc = fmaf(wA, __half2float(h1h[(size_t)sA * DHID + lane]), acc);
    }
    // self-loop + dst-side norm: di*(edge_sum + di*self)
    float di = dinv[i];
    acc = (acc + di * __half2float(h1h[(size_t)i * DHID + lane])) * di;
    acc = fmaxf(acc + bias, 0.0f);
    float o0 = acc * w2a, o1 = acc * w2b;
    for (int off = 32; off > 0; off >>= 1) {
        o0 += __shfl_xor(o0, off);
        o1 += __shfl_xor(o1, off);
    }
    if (lane == 0) {
        h2[i * 2]     = o0;
        h2[i * 2 + 1] = o1;
    }
}

// ------- K8: layer-2 propagate: out = di*(sum + di*self) + b2 ------
__global__ __launch_bounds__(256) void k_prop2(const float* __restrict__ h2,
                                               const int* __restrict__ rp,
                                               const int2* __restrict__ csw,
                                               const float* __restrict__ dinv,
                                               const float* __restrict__ b2,
                                               float* __restrict__ out, int N) {
    const float2* h2v = (const float2*)h2;
    int lane = threadIdx.x & 63;
    int i = (blockIdx.x * 256 + threadIdx.x) >> 6;
    if (i >= N) return;
    int s0 = rp[i], e0 = rp[i + 1];
    float a0 = 0.0f, a1 = 0.0f;
    for (int p = s0 + lane; p < e0; p += 64) {
        int2 ed = csw[p];
        float w = __int_as_float(ed.y) * dinv[ed.x];  // raw w * dinv[src]
        float2 hv = h2v[ed.x];
        a0 = fmaf(w, hv.x, a0);
        a1 = fmaf(w, hv.y, a1);
    }
    for (int off = 32; off > 0; off >>= 1) {
        a0 += __shfl_xor(a0, off);
        a1 += __shfl_xor(a1, off);
    }
    if (lane == 0) {
        float di = dinv[i];
        out[i * 2]     = di * (a0 + di * h2[i * 2])     + b2[0];
        out[i * 2 + 1] = di * (a1 + di * h2[i * 2 + 1]) + b2[1];
    }
}

extern "C" void kernel_launch(void* const* d_in, const int* in_sizes, int n_in,
                              void* d_out, int out_size, void* d_ws, size_t ws_size,
                              hipStream_t stream) {
    const float* x  = (const float*)d_in[0];
    const int*   ei = (const int*)d_in[1];     // int32 per harness contract
    const float* ew = (const float*)d_in[2];
    const float* W1 = (const float*)d_in[3];
    const float* b1 = (const float*)d_in[4];
    const float* W2 = (const float*)d_in[5];
    const float* b2 = (const float*)d_in[6];
    float* out = (float*)d_out;

    const int N = in_sizes[0] / DIN;   // 100000
    const int E = in_sizes[2];         // 3200000

    const int C = 512;                 // edge chunks (6.25K edges each)
    const int B = (N + 127) >> BSH;    // 782 buckets of 128 nodes
    const int chunk = (E + C - 1) / C;

    // workspace layout (~54 MB; ebuf aliased by h1/h2 after k_build)
    char* w0 = (char*)d_ws;
    float* dinv  = (float*)w0;                      // N floats
    int*   rp    = (int*)(dinv + N);                // N+1 ints (+3 pad)
    int*   histT = rp + (N + 4);                    // B*C ints (1.6 MB)
    int*   tot   = histT + (size_t)B * C;           // B ints
    int*   bb    = tot + B;                         // B+1 ints
    size_t off_csw = ((size_t)((char*)(bb + B + 1) - w0) + 15) & ~(size_t)15;
    int2*  csw  = (int2*)(w0 + off_csw);            // E pairs (25.6 MB)
    int2*  ebuf = csw + E;                          // E pairs (25.6 MB)
    __half* h1  = (__half*)ebuf;                    // alias: N*64 fp16 (12.8 MB)
    float* h2   = (float*)(h1 + (size_t)N * DHID);  // alias: N*2 fp32

    k_hist<<<C, 1024, 0, stream>>>(ei, histT, E, chunk, B, C);
    k_scan1<<<B, 512, 0, stream>>>(histT, tot, C);
    k_scan2<<<1, 1024, 0, stream>>>(tot, bb, B);
    k_scatter<<<C, 1024, 0, stream>>>(ei, ew, histT, bb, ebuf, E, chunk, B, C);
    k_build<<<B, 1024, 0, stream>>>(ebuf, bb, rp, dinv, csw, N, E);

    const int GB = (N + 63) / 64;
    k_gemm1<<<GB, 256, 0, stream>>>(x, W1, h1, N);

    const int GW = ((size_t)N * 64 + 255) / 256;   // one wave per node
    k_agg1<<<GW, 256, 0, stream>>>(h1, rp, csw, dinv, b1, W2, h2, N);
    k_prop2<<<GW, 256, 0, stream>>>(h2, rp, csw, dinv, b2, out, N);
}